// Round 11
// baseline (612.323 us; speedup 1.0000x reference)
//
#include <hip/hip_runtime.h>
#include <hip/hip_bf16.h>
#include <stdint.h>
#include <string.h>

#define N_NODES 500000
#define N_EDGES 1000000
#define BATCH   4096
#define KNBR    20
#define DN      172
#define DT      100
#define DOUT    128

#define KSTEPS   6    // ceil(172/32)
#define KSTEPS_T 4    // ceil(100/32) padded to 128
#define NCT      8    // 128 / 16 col tiles
#define CSW      112  // csum row width (bf16), 224 B, 16B-aligned

#define NMARK_E (BATCH * KNBR * KNBR + BATCH * KNBR)   // 1,720,320 edge refs
#define NMARK_N (BATCH * KNBR + BATCH)                 //    86,016 node src refs

#define EBLK 2048     // edge-proj role blocks in k_mix
#define GBLK 1280     // gather-1a role blocks in k_mix  (5:8 interleave, 3328 = 256*13)

typedef __attribute__((ext_vector_type(8))) short   bf16x8;
typedef __attribute__((ext_vector_type(4))) float   f32x4;
typedef __attribute__((ext_vector_type(2))) float   f32x2;

#define INV2PI 0.15915494309189535f

__device__ inline short f2bf(float f) {
    __hip_bfloat16 h = __float2bfloat16(f);
    short s;
    memcpy(&s, &h, 2);
    return s;
}
__device__ inline float bflo(uint32_t u) { return __uint_as_float(u << 16); }
__device__ inline float bfhi(uint32_t u) { return __uint_as_float(u & 0xffff0000u); }
__device__ inline float rfl_f(float x) {
    return __uint_as_float(__builtin_amdgcn_readfirstlane(__float_as_uint(x)));
}
// fp8 e4m3 (OCP on gfx950) pack/unpack via HW converts
__device__ inline unsigned char f2fp8(float f) {
    return (unsigned char)(__builtin_amdgcn_cvt_pk_fp8_f32(f, f, 0, false) & 0xff);
}
__device__ inline f32x2 fp8pair(uint32_t u) {   // low 16 bits = 2 fp8 values
    return __builtin_amdgcn_cvt_pk_f32_fp8((int)u, false);
}

// ---------------------------------------------------------------------------
// Prep (one launch). Block roles:
//   [0,32)    : B-fragment build (1 slot/thread)
//   32        : tconst = cos(phase) @ W_time + b_time
//   [33,545)  : edge liveness mark (emap)
//   [545,577) : node src-row mark (nmap): nbrs_l2 + source_nodes
// ---------------------------------------------------------------------------
__global__ void k_prep(const float* __restrict__ Wn, const float* __restrict__ We,
                       const float* __restrict__ Wt, const float* __restrict__ bt,
                       const float* __restrict__ tp,
                       const int* __restrict__ e1, const int* __restrict__ e2,
                       const int* __restrict__ srcs1, const int* __restrict__ srcs2,
                       short* __restrict__ wnF, short* __restrict__ weF,
                       short* __restrict__ wtF, float* __restrict__ tconst,
                       unsigned char* __restrict__ emap, unsigned char* __restrict__ nmap)
{
    const int NS6 = NCT * KSTEPS * 64;    // 3072
    const int NS4 = NCT * KSTEPS_T * 64;  // 2048
    const int b = blockIdx.x;
    if (b < 32) {
        const int idx = b * 256 + threadIdx.x;   // 8192 = 2*NS6+NS4
        const float* W;
        short* dst;
        int slot, ks;
        if (idx < NS6)          { W = Wn; dst = wnF; slot = idx;           ks = KSTEPS; }
        else if (idx < 2 * NS6) { W = We; dst = weF; slot = idx - NS6;     ks = KSTEPS; }
        else                    { W = Wt; dst = wtF; slot = idx - 2 * NS6; ks = KSTEPS_T; }
        const int kd = (ks == KSTEPS) ? DN : DT;
        int ct  = slot / (ks * 64);
        int rem = slot % (ks * 64);
        int s   = rem / 64;
        int l   = rem % 64;
        int col   = ct * 16 + (l & 15);
        int kbase = s * 32 + (l >> 4) * 8;
        bf16x8 sv;
        #pragma unroll
        for (int j = 0; j < 8; ++j) {
            int k = kbase + j;
            sv[j] = f2bf((k < kd) ? W[k * DOUT + col] : 0.0f);
        }
        *(bf16x8*)(dst + (size_t)slot * 8) = sv;
    } else if (b == 32) {
        const int tid = threadIdx.x;
        if (tid < DOUT) {
            float acc = bt[tid];
            for (int j = 0; j < DT; ++j)
                acc += cosf(tp[j]) * Wt[j * DOUT + tid];
            tconst[tid] = acc;
        }
    } else if (b < 545) {
        const int n1 = BATCH * KNBR * KNBR;
        for (int i = (b - 33) * 256 + threadIdx.x; i < NMARK_E; i += 512 * 256) {
            int e = (i < n1) ? e1[i] : e2[i - n1];
            emap[e] = 1;
        }
    } else {
        const int n1 = BATCH * KNBR;
        for (int i = (b - 545) * 256 + threadIdx.x; i < NMARK_N; i += 32 * 256) {
            int n = (i < n1) ? srcs1[i] : srcs2[i - n1];
            nmap[n] = 1;
        }
    }
}

// ---------------------------------------------------------------------------
// Projection GEMM machinery (persistent + software-pipelined, dbuf in regs).
// ---------------------------------------------------------------------------
#define ALOAD(AV, TILE)                                                        \
    {                                                                          \
        const int row0_ = (TILE) * 64 + wv * 16;                               \
        int r_ = row0_ + r15;                                                  \
        if (r_ > nrows - 1) r_ = nrows - 1;                                    \
        const bool live_ = (rowmap == nullptr) || (rowmap[r_] != 0);           \
        const float* fp_ = feat + (size_t)r_ * DN;                             \
        _Pragma("unroll")                                                      \
        for (int s_ = 0; s_ < KSTEPS; ++s_) {                                  \
            const int k0_ = s_ * 32 + kq * 8;                                  \
            AV[2 * s_]     = (f32x4){0, 0, 0, 0};                              \
            AV[2 * s_ + 1] = (f32x4){0, 0, 0, 0};                              \
            if (live_) {                                                       \
                if (k0_ + 4 <= DN) AV[2 * s_]     = *(const f32x4*)(fp_ + k0_);\
                if (k0_ + 8 <= DN) AV[2 * s_ + 1] = *(const f32x4*)(fp_ + k0_ + 4); \
            }                                                                  \
        }                                                                      \
    }

#define CSTORE(AV, TILE)                                                       \
    {                                                                          \
        f32x4 acc_[NCT];                                                       \
        _Pragma("unroll")                                                      \
        for (int ct_ = 0; ct_ < NCT; ++ct_) acc_[ct_] = (f32x4){0, 0, 0, 0};   \
        _Pragma("unroll")                                                      \
        for (int s_ = 0; s_ < KSTEPS; ++s_) {                                  \
            bf16x8 a_;                                                         \
            _Pragma("unroll")                                                  \
            for (int j_ = 0; j_ < 4; ++j_) a_[j_]     = f2bf(AV[2 * s_][j_]);  \
            _Pragma("unroll")                                                  \
            for (int j_ = 0; j_ < 4; ++j_) a_[4 + j_] = f2bf(AV[2 * s_ + 1][j_]); \
            _Pragma("unroll")                                                  \
            for (int ct_ = 0; ct_ < NCT; ++ct_) {                              \
                bf16x8 b_ = *(const bf16x8*)&lds_b[((ct_ * KSTEPS + s_) * 64 + lane) * 8]; \
                acc_[ct_] = __builtin_amdgcn_mfma_f32_16x16x32_bf16(a_, b_, acc_[ct_], 0, 0, 0); \
            }                                                                  \
        }                                                                      \
        const int rbase_ = (TILE) * 64 + wv * 16 + (lane >> 4) * 4;            \
        _Pragma("unroll")                                                      \
        for (int rr_ = 0; rr_ < 4; ++rr_) {                                    \
            const int grow_ = rbase_ + rr_;                                    \
            if (grow_ < nrows && ((rowmap == nullptr) || rowmap[grow_])) {     \
                const bool s16_ = (out16 != nullptr) && (srcmap[grow_] != 0);  \
                _Pragma("unroll")                                              \
                for (int ct_ = 0; ct_ < NCT; ++ct_) {                          \
                    const float v_ = acc_[ct_][rr_] + bs[ct_];                 \
                    out8[(size_t)grow_ * DOUT + ct_ * 16 + c0] = f2fp8(v_);    \
                    if (s16_)                                                  \
                        out16[(size_t)grow_ * DOUT + ct_ * 16 + c0] = f2bf(v_);\
                }                                                              \
            }                                                                  \
        }                                                                      \
    }

#define PROJ_LOOP(START, STRIDE)                                               \
    {                                                                          \
        int t = (START);                                                       \
        if (t < ntiles) {                                                      \
            f32x4 avA[2 * KSTEPS], avB[2 * KSTEPS];                            \
            ALOAD(avA, t);                                                     \
            for (;;) {                                                         \
                int tn = t + (STRIDE);                                         \
                if (tn < ntiles) ALOAD(avB, tn);                               \
                CSTORE(avA, t);                                                \
                if (tn >= ntiles) break;                                       \
                t = tn;                                                        \
                tn = t + (STRIDE);                                             \
                if (tn < ntiles) ALOAD(avA, tn);                               \
                CSTORE(avB, t);                                                \
                if (tn >= ntiles) break;                                       \
                t = tn;                                                        \
            }                                                                  \
        }                                                                      \
    }

// ---------------------------------------------------------------------------
// Node projection: fp8 table for all rows; bf16 table only for nmap rows.
// ---------------------------------------------------------------------------
__global__ __launch_bounds__(256)
void k_projN(const float* __restrict__ feat, const float* __restrict__ bias,
             const short* __restrict__ wfrag, const unsigned char* __restrict__ nmap,
             short* __restrict__ out16, unsigned char* __restrict__ out8)
{
    __shared__ __attribute__((aligned(16))) short lds_b[NCT * KSTEPS * 64 * 8];  // 48 KB
    const int tid = threadIdx.x, lane = tid & 63, wv = tid >> 6;
    const unsigned char* rowmap = nullptr;
    const unsigned char* srcmap = nmap;
    const int nrows = N_NODES, ntiles = (N_NODES + 63) / 64;

    #pragma unroll
    for (int i = 0; i < 12; ++i)
        ((f32x4*)lds_b)[tid + i * 256] = ((const f32x4*)wfrag)[tid + i * 256];
    __syncthreads();

    const int r15 = lane & 15, kq = lane >> 4, c0 = lane & 15;
    float bs[NCT];
    #pragma unroll
    for (int ct = 0; ct < NCT; ++ct) bs[ct] = bias[ct * 16 + c0];

    PROJ_LOOP(blockIdx.x, gridDim.x);
}

// ---------------------------------------------------------------------------
// Mixed kernel: edge projection (emap-gated, fp8 out) INTERLEAVED with the
// node-message half of gather-1. Roles: blockIdx%13 < 5 -> gather (GBLK=1280),
// else edge-proj (EBLK=2048). Gather writes pcs (cos sums, bf16, /cnt) and
// pmsg (f32: src + tconst + (ms_node + cnt*bt)/cnt).
// ---------------------------------------------------------------------------
__global__ __launch_bounds__(256)
void k_mix(const float* __restrict__ featE, const float* __restrict__ biasE,
           const short* __restrict__ weF, const unsigned char* __restrict__ emap,
           unsigned char* __restrict__ edgeF8,
           const short* __restrict__ node_bf16, const unsigned char* __restrict__ node_f8,
           const int* __restrict__ src_idx, const float* __restrict__ ts_arr,
           const int* __restrict__ nbrs, const float* __restrict__ etime,
           const float* __restrict__ bt, const float* __restrict__ tw,
           const float* __restrict__ tp, const float* __restrict__ tconst,
           short* __restrict__ pcs, float* __restrict__ pmsg)
{
    __shared__ __attribute__((aligned(16))) short lds_b[NCT * KSTEPS * 64 * 8];  // 48 KB
    const int tid = threadIdx.x, lane = tid & 63;
    const int b = blockIdx.x, rr13 = b % 13;

    if (rr13 < 5) {
        // ---- gather-1a role ----
        const int g  = (b / 13) * 5 + rr13;
        const int wv = __builtin_amdgcn_readfirstlane(tid >> 6);
        const int rowbase = g * 64 + wv * 16;
        const int d2 = lane * 2;
        const f32x2 bt2 = *(const f32x2*)&bt[d2];
        const f32x2 tc2 = *(const f32x2*)&tconst[d2];
        const float wr0 = tw[lane] * INV2PI;
        const float pr0 = tp[lane] * INV2PI;
        float wr1 = 0.0f, pr1 = 0.0f;
        if (lane < DT - 64) { wr1 = tw[64 + lane] * INV2PI; pr1 = tp[64 + lane] * INV2PI; }

        for (int i = 0; i < 16; ++i) {
            const int row = rowbase + i;
            const int*   np_ = nbrs  + (size_t)row * KNBR;
            const float* tt_ = etime + (size_t)row * KNBR;
            int nk[KNBR]; float et[KNBR];
            #pragma unroll
            for (int k = 0; k < KNBR; ++k) {
                nk[k] = __builtin_amdgcn_readfirstlane(np_[k]);
                et[k] = rfl_f(tt_[k]);
            }
            const int si = __builtin_amdgcn_readfirstlane(src_idx[row]);
            const float ts = rfl_f(ts_arr[row / KNBR]);

            int cnt = 0;
            #pragma unroll
            for (int k = 0; k < KNBR; ++k) cnt += (nk[k] != 0);

            uint32_t nv[KNBR];
            #pragma unroll
            for (int k = 0; k < KNBR; ++k)
                nv[k] = *(const uint16_t*)(node_f8 + (size_t)nk[k] * DOUT + d2);
            const uint32_t sv = *(const uint32_t*)(node_bf16 + (size_t)si * DOUT + d2);

            const float base0 = fmaf(ts, wr0, pr0);
            const float base1 = fmaf(ts, wr1, pr1);
            float cs0 = 0, cs1 = 0, ms0 = 0, ms1 = 0;
            #pragma unroll
            for (int k = 0; k < KNBR; ++k) {
                const float w = (nk[k] != 0) ? 1.0f : 0.0f;
                float r0 = fmaf(-et[k], wr0, base0); r0 -= floorf(r0);
                float r1 = fmaf(-et[k], wr1, base1); r1 -= floorf(r1);
                cs0 = fmaf(w, __builtin_amdgcn_cosf(r0), cs0);
                cs1 = fmaf(w, __builtin_amdgcn_cosf(r1), cs1);
                f32x2 n2 = fp8pair(nv[k]);
                ms0 = fmaf(w, n2[0], ms0);
                ms1 = fmaf(w, n2[1], ms1);
            }

            const float fc  = (float)cnt;
            const float inv = (cnt > 0) ? 1.0f / fc : 1.0f;

            pcs[(size_t)row * CSW + lane] = f2bf(cs0 * inv);
            if (lane < 48)
                pcs[(size_t)row * CSW + 64 + lane] = f2bf(lane < DT - 64 ? cs1 * inv : 0.0f);

            const float o0 = bflo(sv) + tc2[0] + (ms0 + fc * bt2[0]) * inv;
            const float o1 = bfhi(sv) + tc2[1] + (ms1 + fc * bt2[1]) * inv;
            *(f32x2*)(pmsg + (size_t)row * DOUT + d2) = (f32x2){o0, o1};
        }
        return;
    }

    // ---- edge-projection role ----
    const int e  = (b / 13) * 8 + (rr13 - 5);
    const int wv = tid >> 6;
    const float* feat = featE;
    const unsigned char* rowmap = emap;
    const unsigned char* srcmap = nullptr;
    unsigned char* out8 = edgeF8;
    short* out16 = nullptr;
    const int nrows = N_EDGES, ntiles = (N_EDGES + 63) / 64;

    #pragma unroll
    for (int i = 0; i < 12; ++i)
        ((f32x4*)lds_b)[tid + i * 256] = ((const f32x4*)weF)[tid + i * 256];
    __syncthreads();

    const int r15 = lane & 15, kq = lane >> 4, c0 = lane & 15;
    float bs[NCT];
    #pragma unroll
    for (int ct = 0; ct < NCT; ++ct) bs[ct] = biasE[ct * 16 + c0];

    PROJ_LOOP(e, EBLK);
}

// ---------------------------------------------------------------------------
// Finalize layer 1: edge-msg gather + time-MFMA + write emb1 (bf16).
// 4 waves x 16 rows; pcs tile coop-loaded to LDS; edge sums -> LDS f32;
// per-wave tgemm on its own rows (wave-local after the single barrier).
// ---------------------------------------------------------------------------
__global__ __launch_bounds__(256)
void k_fin(const unsigned char* __restrict__ edge_f8, const short* __restrict__ pcs,
           const float* __restrict__ pmsg,
           const int* __restrict__ nbrs, const int* __restrict__ eidx,
           const short* __restrict__ wtF, short* __restrict__ emb1)
{
    __shared__ __attribute__((aligned(16))) short lds_cs[64][CSW];   // 14 KB
    __shared__ __attribute__((aligned(16))) float lds_ms[64][DOUT];  // 32 KB

    const int tid = threadIdx.x, lane = tid & 63;
    const int wv  = __builtin_amdgcn_readfirstlane(tid >> 6);
    const int base = blockIdx.x * 64;

    for (int i = tid; i < 64 * CSW / 8; i += 256)
        ((bf16x8*)lds_cs)[i] = ((const bf16x8*)(pcs + (size_t)base * CSW))[i];
    __syncthreads();

    const int d2 = lane * 2;
    for (int i = 0; i < 16; ++i) {
        const int row = base + wv * 16 + i, rloc = wv * 16 + i;
        const int* np_ = nbrs + (size_t)row * KNBR;
        const int* ep_ = eidx + (size_t)row * KNBR;
        int nk[KNBR], ek[KNBR];
        #pragma unroll
        for (int k = 0; k < KNBR; ++k) {
            nk[k] = __builtin_amdgcn_readfirstlane(np_[k]);
            ek[k] = __builtin_amdgcn_readfirstlane(ep_[k]);
        }
        int cnt = 0;
        #pragma unroll
        for (int k = 0; k < KNBR; ++k) cnt += (nk[k] != 0);
        const float inv = (cnt > 0) ? 1.0f / (float)cnt : 1.0f;

        uint32_t ev[KNBR];
        #pragma unroll
        for (int k = 0; k < KNBR; ++k)
            ev[k] = *(const uint16_t*)(edge_f8 + (size_t)ek[k] * DOUT + d2);
        const f32x2 pm = *(const f32x2*)(pmsg + (size_t)row * DOUT + d2);

        float ms0 = 0, ms1 = 0;
        #pragma unroll
        for (int k = 0; k < KNBR; ++k) {
            const float w = (nk[k] != 0) ? 1.0f : 0.0f;
            f32x2 e2 = fp8pair(ev[k]);
            ms0 = fmaf(w, e2[0], ms0);
            ms1 = fmaf(w, e2[1], ms1);
        }
        lds_ms[rloc][d2]     = pm[0] + ms0 * inv;
        lds_ms[rloc][d2 + 1] = pm[1] + ms1 * inv;
    }

    // tgemm on this wave's own 16 rows (wave-local LDS deps only)
    const int r15 = lane & 15, kq = lane >> 4, c0 = lane & 15;
    const int row0l = wv * 16;

    f32x4 acc[NCT];
    #pragma unroll
    for (int ct = 0; ct < NCT; ++ct) acc[ct] = (f32x4){0, 0, 0, 0};

    #pragma unroll
    for (int s = 0; s < KSTEPS_T; ++s) {
        const int k0 = s * 32 + kq * 8;
        bf16x8 a = (bf16x8)(short)0;
        if (k0 + 8 <= CSW) a = *(const bf16x8*)&lds_cs[row0l + r15][k0];
        #pragma unroll
        for (int ct = 0; ct < NCT; ++ct) {
            bf16x8 bvec = *(const bf16x8*)(wtF + ((ct * KSTEPS_T + s) * 64 + lane) * 8);
            acc[ct] = __builtin_amdgcn_mfma_f32_16x16x32_bf16(a, bvec, acc[ct], 0, 0, 0);
        }
    }

    const int rloc0 = row0l + (lane >> 4) * 4;
    #pragma unroll
    for (int ct = 0; ct < NCT; ++ct) {
        const int c = ct * 16 + c0;
        #pragma unroll
        for (int rr = 0; rr < 4; ++rr) {
            const int rl = rloc0 + rr;
            emb1[(size_t)(base + rl) * DOUT + c] = f2bf(lds_ms[rl][c] + acc[ct][rr]);
        }
    }
}

// ---------------------------------------------------------------------------
// Layer 2 (fused gather + tgemm), 4 waves x 16 rows, f32 out to d_out.
// ---------------------------------------------------------------------------
__global__ __launch_bounds__(256)
void k_g2(const short* __restrict__ node_bf16, const unsigned char* __restrict__ edge_f8,
          const short* __restrict__ emb1_tab,
          const int* __restrict__ src_idx, const float* __restrict__ ts_arr,
          const int* __restrict__ nbrs, const int* __restrict__ eidx,
          const float* __restrict__ etime,
          const float* __restrict__ bt, const float* __restrict__ tw,
          const float* __restrict__ tp, const float* __restrict__ tconst,
          const short* __restrict__ wtF, float* __restrict__ out_f32)
{
    __shared__ __attribute__((aligned(16))) short lds_cs[64][CSW];   // 14 KB
    __shared__ __attribute__((aligned(16))) float lds_pm[64][DOUT];  // 32 KB

    const int tid = threadIdx.x, lane = tid & 63;
    const int wv  = __builtin_amdgcn_readfirstlane(tid >> 6);
    const int rowbase = blockIdx.x * 64 + wv * 16;

    const int d2 = lane * 2;
    const f32x2 bt2 = *(const f32x2*)&bt[d2];
    const f32x2 tc2 = *(const f32x2*)&tconst[d2];
    const float wr0 = tw[lane] * INV2PI;
    const float pr0 = tp[lane] * INV2PI;
    float wr1 = 0.0f, pr1 = 0.0f;
    if (lane < DT - 64) { wr1 = tw[64 + lane] * INV2PI; pr1 = tp[64 + lane] * INV2PI; }

    for (int i = 0; i < 16; ++i) {
        const int row = rowbase + i, rloc = wv * 16 + i;
        const int*   np_ = nbrs  + (size_t)row * KNBR;
        const int*   ep_ = eidx  + (size_t)row * KNBR;
        const float* tt_ = etime + (size_t)row * KNBR;
        int nk[KNBR], ek[KNBR]; float et[KNBR];
        #pragma unroll
        for (int k = 0; k < KNBR; ++k) {
            nk[k] = __builtin_amdgcn_readfirstlane(np_[k]);
            ek[k] = __builtin_amdgcn_readfirstlane(ep_[k]);
            et[k] = rfl_f(tt_[k]);
        }
        const int si = __builtin_amdgcn_readfirstlane(src_idx[row]);
        const float ts = rfl_f(ts_arr[row]);

        int cnt = 0;
        #pragma unroll
        for (int k = 0; k < KNBR; ++k) cnt += (nk[k] != 0);

        uint32_t ev[KNBR], nv[KNBR];
        #pragma unroll
        for (int k = 0; k < KNBR; ++k)
            ev[k] = *(const uint16_t*)(edge_f8 + (size_t)ek[k] * DOUT + d2);
        #pragma unroll
        for (int k = 0; k < KNBR; ++k)
            nv[k] = *(const uint32_t*)(emb1_tab + ((size_t)row * KNBR + k) * DOUT + d2);
        const uint32_t sv = *(const uint32_t*)(node_bf16 + (size_t)si * DOUT + d2);

        const float base0 = fmaf(ts, wr0, pr0);
        const float base1 = fmaf(ts, wr1, pr1);
        float cs0 = 0, cs1 = 0, ms0 = 0, ms1 = 0;
        #pragma unroll
        for (int k = 0; k < KNBR; ++k) {
            const float w = (nk[k] != 0) ? 1.0f : 0.0f;
            float r0 = fmaf(-et[k], wr0, base0); r0 -= floorf(r0);
            float r1 = fmaf(-et[k], wr1, base1); r1 -= floorf(r1);
            cs0 = fmaf(w, __builtin_amdgcn_cosf(r0), cs0);
            cs1 = fmaf(w, __builtin_amdgcn_cosf(r1), cs1);
            f32x2 e2 = fp8pair(ev[k]);
            ms0 = fmaf(w, e2[0] + bflo(nv[k]), ms0);
            ms1 = fmaf(w, e2[1] + bfhi(nv[k]), ms1);
        }

        const float fc  = (float)cnt;
        const float inv = (cnt > 0) ? 1.0f / fc : 1.0f;

        lds_cs[rloc][lane] = f2bf(cs0 * inv);
        if (lane < 48)
            lds_cs[rloc][64 + lane] = f2bf(lane < DT - 64 ? cs1 * inv : 0.0f);

        lds_pm[rloc][d2]     = bflo(sv) + tc2[0] + (ms0 + fc * bt2[0]) * inv;
        lds_pm[rloc][d2 + 1] = bfhi(sv) + tc2[1] + (ms1 + fc * bt2[1]) * inv;
    }

    const int r15 = lane & 15, kq = lane >> 4, c0 = lane & 15;
    const int row0l = wv * 16;

    f32x4 acc[NCT];
    #pragma unroll
    for (int ct = 0; ct < NCT; ++ct) acc[ct] = (f32x4){0, 0, 0, 0};

    #pragma unroll
    for (int s = 0; s < KSTEPS_T; ++s) {
        const int k0 = s * 32 + kq * 8;
        bf16x8 a = (bf16x8)(short)0;
        if (k0 + 8 <= CSW) a = *(const bf16x8*)&lds_cs[row0l + r15][k0];
        #pragma unroll
        for (int ct = 0; ct < NCT; ++ct) {
            bf16x8 bvec = *(const bf16x8*)(wtF + ((ct * KSTEPS_T + s) * 64 + lane) * 8);
            acc[ct] = __builtin_amdgcn_mfma_f32_16x16x32_bf16(a, bvec, acc[ct], 0, 0, 0);
        }
    }

    const int rloc0 = row0l + (lane >> 4) * 4;
    #pragma unroll
    for (int ct = 0; ct < NCT; ++ct) {
        const int c = ct * 16 + c0;
        #pragma unroll
        for (int rr = 0; rr < 4; ++rr) {
            const int rl = rloc0 + rr;
            out_f32[(size_t)(blockIdx.x * 64 + rl) * DOUT + c] = lds_pm[rl][c] + acc[ct][rr];
        }
    }
}

// ---------------------------------------------------------------------------
extern "C" void kernel_launch(void* const* d_in, const int* in_sizes, int n_in,
                              void* d_out, int out_size, void* d_ws, size_t ws_size,
                              hipStream_t stream)
{
    const float* node_features = (const float*)d_in[0];
    const float* edge_features = (const float*)d_in[1];
    const float* W_node  = (const float*)d_in[2];
    const float* b_node  = (const float*)d_in[3];
    const float* W_time  = (const float*)d_in[4];
    const float* b_time  = (const float*)d_in[5];
    const float* W_edge  = (const float*)d_in[6];
    const float* b_edge  = (const float*)d_in[7];
    const float* time_w  = (const float*)d_in[8];
    const float* time_ph = (const float*)d_in[9];
    const int*   source_nodes = (const int*)d_in[10];
    const float* timestamps   = (const float*)d_in[11];
    const int*   nbrs_l2  = (const int*)d_in[12];
    const int*   eidx_l2  = (const int*)d_in[13];
    const float* etime_l2 = (const float*)d_in[14];
    const int*   nbrs_l1  = (const int*)d_in[15];
    const int*   eidx_l1  = (const int*)d_in[16];
    const float* etime_l1 = (const float*)d_in[17];

    // workspace layout (offsets 256B-aligned)
    char*  ws        = (char*)d_ws;
    short* node_bf16 = (short*)(ws);                            // 128,000,000
    unsigned char* edge_f8 = (unsigned char*)(ws + 128000000);  // 128,000,000
    unsigned char* node_f8 = (unsigned char*)(ws + 256000000);  //  64,000,000
    short* emb1      = (short*)(ws + 320000000);                //  20,971,520
    short* pcs       = (short*)(ws + 340971520);                //  18,350,080
    float* pmsg      = (float*)(ws + 359321600);                //  41,943,040
    float* tconst    = (float*)(ws + 401264640);                //         512
    short* wnF       = (short*)(ws + 401265152);                //      49,152
    short* weF       = (short*)(ws + 401314304);                //      49,152
    short* wtF       = (short*)(ws + 401363456);                //      32,768
    unsigned char* emap = (unsigned char*)(ws + 401396224);     //   1,000,000
    unsigned char* nmap = (unsigned char*)(ws + 402396224);     //     500,224
    if (ws_size < 403000000ull) return;

    hipMemsetAsync(emap, 0, N_EDGES + 500224, stream);   // emap + nmap contiguous

    k_prep<<<577, 256, 0, stream>>>(W_node, W_edge, W_time, b_time, time_ph,
                                    eidx_l1, eidx_l2, nbrs_l2, source_nodes,
                                    wnF, weF, wtF, tconst, emap, nmap);

    k_projN<<<2048, 256, 0, stream>>>(node_features, b_node, wnF, nmap,
                                      node_bf16, node_f8);

    k_mix<<<EBLK + GBLK, 256, 0, stream>>>(
        edge_features, b_edge, weF, emap, edge_f8,
        node_bf16, node_f8, nbrs_l2, timestamps, nbrs_l1, etime_l1,
        b_time, time_w, time_ph, tconst, pcs, pmsg);

    k_fin<<<(BATCH * KNBR) / 64, 256, 0, stream>>>(
        edge_f8, pcs, pmsg, nbrs_l1, eidx_l1, wtF, emb1);

    k_g2<<<BATCH / 64, 256, 0, stream>>>(
        node_bf16, edge_f8, emb1, source_nodes, timestamps,
        nbrs_l2, eidx_l2, etime_l2,
        b_time, time_w, time_ph, tconst, wtF, (float*)d_out);
}

// Round 12
// 447.920 us; speedup vs baseline: 1.3670x; 1.3670x over previous
//
#include <hip/hip_runtime.h>
#include <hip/hip_bf16.h>
#include <stdint.h>
#include <string.h>

#define N_NODES 500000
#define N_EDGES 1000000
#define BATCH   4096
#define KNBR    20
#define DN      172
#define DT      100
#define DOUT    128

#define KSTEPS   6    // ceil(172/32)
#define KSTEPS_T 4    // ceil(100/32) padded to 128
#define NCT      8    // 128 / 16 col tiles
#define CSW      112  // csum row width (bf16), 224 B, 16B-aligned

#define NMARK_E (BATCH * KNBR * KNBR + BATCH * KNBR)   // 1,720,320 edge refs
#define NMARK_N (BATCH * KNBR + BATCH)                 //    86,016 node src refs

#define NBLK_N  800
#define NBLK_E  1248

typedef __attribute__((ext_vector_type(8))) short   bf16x8;
typedef __attribute__((ext_vector_type(4))) float   f32x4;
typedef __attribute__((ext_vector_type(2))) float   f32x2;

#define INV2PI 0.15915494309189535f

__device__ inline short f2bf(float f) {
    __hip_bfloat16 h = __float2bfloat16(f);
    short s;
    memcpy(&s, &h, 2);
    return s;
}
__device__ inline float bflo(uint32_t u) { return __uint_as_float(u << 16); }
__device__ inline float bfhi(uint32_t u) { return __uint_as_float(u & 0xffff0000u); }
__device__ inline float rfl_f(float x) {
    return __uint_as_float(__builtin_amdgcn_readfirstlane(__float_as_uint(x)));
}
// fp8 e4m3 (OCP on gfx950) pack/unpack via HW converts
__device__ inline unsigned char f2fp8(float f) {
    return (unsigned char)(__builtin_amdgcn_cvt_pk_fp8_f32(f, f, 0, false) & 0xff);
}
__device__ inline f32x2 fp8pair(uint32_t u) {   // low 16 bits = 2 fp8 values
    return __builtin_amdgcn_cvt_pk_f32_fp8((int)u, false);
}

// ---------------------------------------------------------------------------
// Prep (one launch). Block roles:
//   [0,32)    : B-fragment build (1 slot/thread)
//   32        : tconst = cos(phase) @ W_time + b_time
//   [33,545)  : edge liveness mark (emap)
//   [545,577) : node src-row mark (nmap): nbrs_l2 + source_nodes
// emap/nmap zeroed by hipMemsetAsync before this kernel.
// ---------------------------------------------------------------------------
__global__ void k_prep(const float* __restrict__ Wn, const float* __restrict__ We,
                       const float* __restrict__ Wt, const float* __restrict__ bt,
                       const float* __restrict__ tp,
                       const int* __restrict__ e1, const int* __restrict__ e2,
                       const int* __restrict__ srcs1, const int* __restrict__ srcs2,
                       short* __restrict__ wnF, short* __restrict__ weF,
                       short* __restrict__ wtF, float* __restrict__ tconst,
                       unsigned char* __restrict__ emap, unsigned char* __restrict__ nmap)
{
    const int NS6 = NCT * KSTEPS * 64;    // 3072
    const int NS4 = NCT * KSTEPS_T * 64;  // 2048
    const int b = blockIdx.x;
    if (b < 32) {
        const int idx = b * 256 + threadIdx.x;   // 8192 = 2*NS6+NS4
        const float* W;
        short* dst;
        int slot, ks;
        if (idx < NS6)          { W = Wn; dst = wnF; slot = idx;           ks = KSTEPS; }
        else if (idx < 2 * NS6) { W = We; dst = weF; slot = idx - NS6;     ks = KSTEPS; }
        else                    { W = Wt; dst = wtF; slot = idx - 2 * NS6; ks = KSTEPS_T; }
        const int kd = (ks == KSTEPS) ? DN : DT;
        int ct  = slot / (ks * 64);
        int rem = slot % (ks * 64);
        int s   = rem / 64;
        int l   = rem % 64;
        int col   = ct * 16 + (l & 15);
        int kbase = s * 32 + (l >> 4) * 8;
        bf16x8 sv;
        #pragma unroll
        for (int j = 0; j < 8; ++j) {
            int k = kbase + j;
            sv[j] = f2bf((k < kd) ? W[k * DOUT + col] : 0.0f);
        }
        *(bf16x8*)(dst + (size_t)slot * 8) = sv;
    } else if (b == 32) {
        const int tid = threadIdx.x;
        if (tid < DOUT) {
            float acc = bt[tid];
            for (int j = 0; j < DT; ++j)
                acc += cosf(tp[j]) * Wt[j * DOUT + tid];
            tconst[tid] = acc;
        }
    } else if (b < 545) {
        const int n1 = BATCH * KNBR * KNBR;
        for (int i = (b - 33) * 256 + threadIdx.x; i < NMARK_E; i += 512 * 256) {
            int e = (i < n1) ? e1[i] : e2[i - n1];
            emap[e] = 1;
        }
    } else {
        const int n1 = BATCH * KNBR;
        for (int i = (b - 545) * 256 + threadIdx.x; i < NMARK_N; i += 32 * 256) {
            int n = (i < n1) ? srcs1[i] : srcs2[i - n1];
            nmap[n] = 1;
        }
    }
}

// ---------------------------------------------------------------------------
// Merged projection GEMM (nodes + edges), persistent + software-pipelined.
// Nodes: fp8 table for all rows; bf16 table ONLY for nmap-marked rows.
// Edges: fp8 table only, emap-gated (loads and stores skipped for dead rows).
// ---------------------------------------------------------------------------
#define ALOAD(AV, TILE)                                                        \
    {                                                                          \
        const int row0_ = (TILE) * 64 + wv * 16;                               \
        int r_ = row0_ + r15;                                                  \
        if (r_ > nrows - 1) r_ = nrows - 1;                                    \
        const bool live_ = (rowmap == nullptr) || (rowmap[r_] != 0);           \
        const float* fp_ = feat + (size_t)r_ * DN;                             \
        _Pragma("unroll")                                                      \
        for (int s_ = 0; s_ < KSTEPS; ++s_) {                                  \
            const int k0_ = s_ * 32 + kq * 8;                                  \
            AV[2 * s_]     = (f32x4){0, 0, 0, 0};                              \
            AV[2 * s_ + 1] = (f32x4){0, 0, 0, 0};                              \
            if (live_) {                                                       \
                if (k0_ + 4 <= DN) AV[2 * s_]     = *(const f32x4*)(fp_ + k0_);\
                if (k0_ + 8 <= DN) AV[2 * s_ + 1] = *(const f32x4*)(fp_ + k0_ + 4); \
            }                                                                  \
        }                                                                      \
    }

#define CSTORE(AV, TILE)                                                       \
    {                                                                          \
        f32x4 acc_[NCT];                                                       \
        _Pragma("unroll")                                                      \
        for (int ct_ = 0; ct_ < NCT; ++ct_) acc_[ct_] = (f32x4){0, 0, 0, 0};   \
        _Pragma("unroll")                                                      \
        for (int s_ = 0; s_ < KSTEPS; ++s_) {                                  \
            bf16x8 a_;                                                         \
            _Pragma("unroll")                                                  \
            for (int j_ = 0; j_ < 4; ++j_) a_[j_]     = f2bf(AV[2 * s_][j_]);  \
            _Pragma("unroll")                                                  \
            for (int j_ = 0; j_ < 4; ++j_) a_[4 + j_] = f2bf(AV[2 * s_ + 1][j_]); \
            _Pragma("unroll")                                                  \
            for (int ct_ = 0; ct_ < NCT; ++ct_) {                              \
                bf16x8 b_ = *(const bf16x8*)&lds_b[((ct_ * KSTEPS + s_) * 64 + lane) * 8]; \
                acc_[ct_] = __builtin_amdgcn_mfma_f32_16x16x32_bf16(a_, b_, acc_[ct_], 0, 0, 0); \
            }                                                                  \
        }                                                                      \
        const int rbase_ = (TILE) * 64 + wv * 16 + (lane >> 4) * 4;            \
        _Pragma("unroll")                                                      \
        for (int rr_ = 0; rr_ < 4; ++rr_) {                                    \
            const int grow_ = rbase_ + rr_;                                    \
            if (grow_ < nrows && ((rowmap == nullptr) || rowmap[grow_])) {     \
                const bool s16_ = (out16 != nullptr) && (srcmap[grow_] != 0);  \
                _Pragma("unroll")                                              \
                for (int ct_ = 0; ct_ < NCT; ++ct_) {                          \
                    const float v_ = acc_[ct_][rr_] + bs[ct_];                 \
                    out8[(size_t)grow_ * DOUT + ct_ * 16 + c0] = f2fp8(v_);    \
                    if (s16_)                                                  \
                        out16[(size_t)grow_ * DOUT + ct_ * 16 + c0] = f2bf(v_);\
                }                                                              \
            }                                                                  \
        }                                                                      \
    }

__global__ __launch_bounds__(256)
void k_proj2(const float* __restrict__ featN, const float* __restrict__ biasN,
             const short* __restrict__ wnF, short* __restrict__ nodeBF,
             unsigned char* __restrict__ nodeF8, const unsigned char* __restrict__ nmap,
             const float* __restrict__ featE, const float* __restrict__ biasE,
             const short* __restrict__ weF, const unsigned char* __restrict__ emap,
             unsigned char* __restrict__ edgeF8)
{
    __shared__ __attribute__((aligned(16))) short lds_b[NCT * KSTEPS * 64 * 8];  // 48 KB
    const int tid = threadIdx.x, lane = tid & 63, wv = tid >> 6;

    const bool edge = (blockIdx.x >= NBLK_N);
    const int  bid  = edge ? blockIdx.x - NBLK_N : blockIdx.x;
    const int  nblk = edge ? NBLK_E : NBLK_N;
    const float* feat = edge ? featE : featN;
    const float* bias = edge ? biasE : biasN;
    const short* wfrag = edge ? weF : wnF;
    const unsigned char* rowmap = edge ? emap : nullptr;
    const unsigned char* srcmap = nmap;
    unsigned char* out8 = edge ? edgeF8 : nodeF8;
    short* out16 = edge ? nullptr : nodeBF;
    const int nrows  = edge ? N_EDGES : N_NODES;
    const int ntiles = (nrows + 63) / 64;

    #pragma unroll
    for (int i = 0; i < 12; ++i)
        ((f32x4*)lds_b)[tid + i * 256] = ((const f32x4*)wfrag)[tid + i * 256];
    __syncthreads();

    const int r15 = lane & 15, kq = lane >> 4, c0 = lane & 15;
    float bs[NCT];
    #pragma unroll
    for (int ct = 0; ct < NCT; ++ct) bs[ct] = bias[ct * 16 + c0];

    int t = bid;
    if (t >= ntiles) return;

    f32x4 avA[2 * KSTEPS], avB[2 * KSTEPS];
    ALOAD(avA, t);
    for (;;) {
        int tn = t + nblk;
        if (tn < ntiles) ALOAD(avB, tn);
        CSTORE(avA, t);
        if (tn >= ntiles) break;
        t = tn;
        tn = t + nblk;
        if (tn < ntiles) ALOAD(avA, tn);
        CSTORE(avB, t);
        if (tn >= ntiles) break;
        t = tn;
    }
}

// ---------------------------------------------------------------------------
// Fused gather + time-GEMM. WPB waves/block, 64 rows/block; wave wv gathers
// rows [wv*(64/WPB), ...+64/WPB) (csum + partial -> LDS), then after a barrier
// runs a tgemm slice: WPB=8 -> wave (wv) does row-tile (wv>>1), col half
// (wv&1); WPB=4 -> wave wv does row-tile wv, all 8 col tiles.
// L1: partial bf16, out bf16 (emb1).  L2: partial f32, out f32 (d_out).
// ---------------------------------------------------------------------------
template <bool L2, int WPB>
__global__ __launch_bounds__(WPB * 64)
void k_gfused(const short* __restrict__ node_bf16, const unsigned char* __restrict__ edge_f8,
              const unsigned char* __restrict__ node_f8, const short* __restrict__ emb1_tab,
              const int* __restrict__ src_idx, const float* __restrict__ ts_arr,
              const int* __restrict__ nbrs, const int* __restrict__ eidx,
              const float* __restrict__ etime,
              const float* __restrict__ bt, const float* __restrict__ tw,
              const float* __restrict__ tp, const float* __restrict__ tconst,
              const short* __restrict__ wtF,
              float* __restrict__ out_f32, short* __restrict__ out_bf16)
{
    __shared__ __attribute__((aligned(16))) short lds_cs[64][CSW];           // 14 KB
    __shared__ __attribute__((aligned(16))) unsigned char lds_pm[64 * DOUT * (L2 ? 4 : 2)];

    const int tid = threadIdx.x, lane = tid & 63;
    const int wv  = __builtin_amdgcn_readfirstlane(tid >> 6);
    const int RPW = 64 / WPB;
    const int rowbase = blockIdx.x * 64 + wv * RPW;

    const int d2 = lane * 2;
    const f32x2 bt2 = *(const f32x2*)&bt[d2];
    const f32x2 tc2 = *(const f32x2*)&tconst[d2];
    const float wr0 = tw[lane] * INV2PI;
    const float pr0 = tp[lane] * INV2PI;
    float wr1 = 0.0f, pr1 = 0.0f;
    if (lane < DT - 64) { wr1 = tw[64 + lane] * INV2PI; pr1 = tp[64 + lane] * INV2PI; }

    // ---- gather phase: RPW rows sequentially ----
    for (int i = 0; i < RPW; ++i) {
        const int row  = rowbase + i;
        const int rloc = wv * RPW + i;

        const int*   np_ = nbrs  + (size_t)row * KNBR;
        const int*   ep_ = eidx  + (size_t)row * KNBR;
        const float* tt_ = etime + (size_t)row * KNBR;
        int   nk[KNBR], ek[KNBR];
        float et[KNBR];
        #pragma unroll
        for (int k = 0; k < KNBR; ++k) {
            nk[k] = __builtin_amdgcn_readfirstlane(np_[k]);
            ek[k] = __builtin_amdgcn_readfirstlane(ep_[k]);
            et[k] = rfl_f(tt_[k]);
        }
        const int si = __builtin_amdgcn_readfirstlane(src_idx[row]);
        const float ts = rfl_f(L2 ? ts_arr[row] : ts_arr[row / KNBR]);

        int cnt = 0;
        #pragma unroll
        for (int k = 0; k < KNBR; ++k) cnt += (nk[k] != 0);

        uint32_t ev[KNBR], nv[KNBR];
        #pragma unroll
        for (int k = 0; k < KNBR; ++k)
            ev[k] = *(const uint16_t*)(edge_f8 + (size_t)ek[k] * DOUT + d2);
        #pragma unroll
        for (int k = 0; k < KNBR; ++k) {
            if (L2) nv[k] = *(const uint32_t*)(emb1_tab + ((size_t)row * KNBR + k) * DOUT + d2);
            else    nv[k] = *(const uint16_t*)(node_f8 + (size_t)nk[k] * DOUT + d2);
        }
        const uint32_t sv = *(const uint32_t*)(node_bf16 + (size_t)si * DOUT + d2);

        const float base0 = fmaf(ts, wr0, pr0);
        const float base1 = fmaf(ts, wr1, pr1);

        float cs0 = 0, cs1 = 0, ms0 = 0, ms1 = 0;
        #pragma unroll
        for (int k = 0; k < KNBR; ++k) {
            const float w = (nk[k] != 0) ? 1.0f : 0.0f;
            float r0 = fmaf(-et[k], wr0, base0); r0 -= floorf(r0);
            float r1 = fmaf(-et[k], wr1, base1); r1 -= floorf(r1);
            cs0 = fmaf(w, __builtin_amdgcn_cosf(r0), cs0);
            cs1 = fmaf(w, __builtin_amdgcn_cosf(r1), cs1);
            f32x2 e2 = fp8pair(ev[k]);
            float nlo, nhi;
            if (L2) { nlo = bflo(nv[k]); nhi = bfhi(nv[k]); }
            else    { f32x2 n2 = fp8pair(nv[k]); nlo = n2[0]; nhi = n2[1]; }
            ms0 = fmaf(w, e2[0] + nlo, ms0);
            ms1 = fmaf(w, e2[1] + nhi, ms1);
        }

        const float fc  = (float)cnt;
        const float inv = (cnt > 0) ? 1.0f / fc : 1.0f;

        lds_cs[rloc][lane] = f2bf(cs0 * inv);
        if (lane < 48)
            lds_cs[rloc][64 + lane] = f2bf(lane < DT - 64 ? cs1 * inv : 0.0f);

        const float o0 = bflo(sv) + tc2[0] + (ms0 + fc * bt2[0]) * inv;
        const float o1 = bfhi(sv) + tc2[1] + (ms1 + fc * bt2[1]) * inv;
        if (L2) {
            *(f32x2*)&((float*)lds_pm)[rloc * DOUT + d2] = (f32x2){o0, o1};
        } else {
            uint32_t u = (uint32_t)(uint16_t)f2bf(o0) | ((uint32_t)(uint16_t)f2bf(o1) << 16);
            *(uint32_t*)&((short*)lds_pm)[rloc * DOUT + d2] = u;
        }
    }

    if (WPB == 8) __syncthreads();   // tgemm tiles span 2 waves' gathered rows

    // ---- tgemm phase ----
    const int r15 = lane & 15, kq = lane >> 4, c0 = lane & 15;
    const int tile  = (WPB == 8) ? (wv >> 1) : wv;       // 16-row tile index
    const int ctb   = (WPB == 8) ? (wv & 1) * 4 : 0;     // col-tile base
    const int NCTW  = (WPB == 8) ? 4 : 8;
    const int row0l = tile * 16;

    f32x4 acc[NCTW == 4 ? 4 : 8];
    #pragma unroll
    for (int ct = 0; ct < NCTW; ++ct) acc[ct] = (f32x4){0, 0, 0, 0};

    #pragma unroll
    for (int s = 0; s < KSTEPS_T; ++s) {
        const int k0 = s * 32 + kq * 8;
        bf16x8 a = (bf16x8)(short)0;
        if (k0 + 8 <= CSW) a = *(const bf16x8*)&lds_cs[row0l + r15][k0];
        #pragma unroll
        for (int ct = 0; ct < NCTW; ++ct) {
            bf16x8 b = *(const bf16x8*)(wtF + (((ctb + ct) * KSTEPS_T + s) * 64 + lane) * 8);
            acc[ct] = __builtin_amdgcn_mfma_f32_16x16x32_bf16(a, b, acc[ct], 0, 0, 0);
        }
    }

    const int rloc0 = row0l + (lane >> 4) * 4;
    #pragma unroll
    for (int ct = 0; ct < NCTW; ++ct) {
        const int c = (ctb + ct) * 16 + c0;
        #pragma unroll
        for (int rr = 0; rr < 4; ++rr) {
            const int rl = rloc0 + rr;
            const size_t go = (size_t)(blockIdx.x * 64 + rl) * DOUT + c;
            if (L2) {
                float pmv = ((const float*)lds_pm)[rl * DOUT + c];
                out_f32[go] = pmv + acc[ct][rr];
            } else {
                float pmv = bflo((uint32_t)(uint16_t)((const short*)lds_pm)[rl * DOUT + c]);
                out_bf16[go] = f2bf(pmv + acc[ct][rr]);
            }
        }
    }
}

// ---------------------------------------------------------------------------
extern "C" void kernel_launch(void* const* d_in, const int* in_sizes, int n_in,
                              void* d_out, int out_size, void* d_ws, size_t ws_size,
                              hipStream_t stream)
{
    const float* node_features = (const float*)d_in[0];
    const float* edge_features = (const float*)d_in[1];
    const float* W_node  = (const float*)d_in[2];
    const float* b_node  = (const float*)d_in[3];
    const float* W_time  = (const float*)d_in[4];
    const float* b_time  = (const float*)d_in[5];
    const float* W_edge  = (const float*)d_in[6];
    const float* b_edge  = (const float*)d_in[7];
    const float* time_w  = (const float*)d_in[8];
    const float* time_ph = (const float*)d_in[9];
    const int*   source_nodes = (const int*)d_in[10];
    const float* timestamps   = (const float*)d_in[11];
    const int*   nbrs_l2  = (const int*)d_in[12];
    const int*   eidx_l2  = (const int*)d_in[13];
    const float* etime_l2 = (const float*)d_in[14];
    const int*   nbrs_l1  = (const int*)d_in[15];
    const int*   eidx_l1  = (const int*)d_in[16];
    const float* etime_l1 = (const float*)d_in[17];

    // workspace layout (all offsets 256B-aligned)
    char*  ws        = (char*)d_ws;
    short* node_bf16 = (short*)(ws);                        // 128,000,000
    unsigned char* edge_f8 = (unsigned char*)(ws + 128000000);  // 128,000,000
    unsigned char* node_f8 = (unsigned char*)(ws + 256000000);  //  64,000,000
    short* emb1      = (short*)(ws + 320000000);            //  20,971,520 (bf16)
    float* tconst    = (float*)(ws + 340971520);            //         512
    short* wnF       = (short*)(ws + 340972032);            //      49,152
    short* weF       = (short*)(ws + 341021184);            //      49,152
    short* wtF       = (short*)(ws + 341070336);            //      32,768
    unsigned char* emap = (unsigned char*)(ws + 341103104); //   1,000,000
    unsigned char* nmap = (unsigned char*)(ws + 342103104); //     500,224 -> 342,603,328
    if (ws_size < 342700000ull) return;

    hipMemsetAsync(emap, 0, N_EDGES + 500224, stream);   // emap + nmap contiguous

    k_prep<<<577, 256, 0, stream>>>(W_node, W_edge, W_time, b_time, time_ph,
                                    eidx_l1, eidx_l2, nbrs_l2, source_nodes,
                                    wnF, weF, wtF, tconst, emap, nmap);

    k_proj2<<<NBLK_N + NBLK_E, 256, 0, stream>>>(
        node_features, b_node, wnF, node_bf16, node_f8, nmap,
        edge_features, b_edge, weF, emap, edge_f8);

    // layer 1: 81920 rows = 1280 blocks x 64; 8 waves/block (32 waves/CU TLP)
    k_gfused<false, 8><<<(BATCH * KNBR) / 64, 512, 0, stream>>>(
        node_bf16, edge_f8, node_f8, emb1, nbrs_l2,
        timestamps, nbrs_l1, eidx_l1, etime_l1,
        b_time, time_w, time_ph, tconst, wtF,
        nullptr, emb1);

    // layer 2: 4096 rows = 64 blocks x 64; 4 waves/block (f32 partial in LDS)
    k_gfused<true, 4><<<BATCH / 64, 256, 0, stream>>>(
        node_bf16, edge_f8, node_f8, emb1, source_nodes,
        timestamps, nbrs_l2, eidx_l2, etime_l2,
        b_time, time_w, time_ph, tconst, wtF,
        (float*)d_out, nullptr);
}